// Round 15
// baseline (107.798 us; speedup 1.0000x reference)
//
#include <hip/hip_runtime.h>
#include <hip/hip_bf16.h>
#include <stdint.h>

typedef __attribute__((ext_vector_type(8))) short short8;
typedef __attribute__((ext_vector_type(4))) float f32x4;

#define NB 128
#define NL 256
#define NROWS 32768        // B*L
#define IN_DIM 360
#define KP1 384            // padded K for layer-1 GEMM (permuted layout)
#define MEM 200
#define NP 256             // padded N
#define OUT_X (NROWS * MEM)
#define YTP 264            // Yt pitch in bf16 (528 B rows)
#define BUFSZ 20480        // one staging buffer: At 16K + Bt 4K
#define YTOFF 40960        // Yt offset in smem

// Permuted K layout for x/W0p (keeps every 8-col chunk single-table):
//   kp 0..299 emb | kp 304..333 pos | kp 336..365 ner | else zero
// Chunk id c = kp/8: 0..36 emb-full | 37 emb-tail | 38..41 pos | 42..45 ner | 46,47 zero

__device__ __forceinline__ unsigned short f2b(float f) {
    unsigned u = __builtin_bit_cast(unsigned, f);
    unsigned r = (u + 0x7FFFu + ((u >> 16) & 1u)) >> 16;
    return (unsigned short)r;
}

// gather one 8-col chunk of the (permuted) embedding row as bf16
__device__ __forceinline__ short8 gather_chunk(int chunk, const float* __restrict__ er,
                                               const float* __restrict__ pr,
                                               const float* __restrict__ nr) {
    float v[8];
    if (chunk < 37) {                                   // emb, 16B-aligned (stride 1200 B)
        const float* s = er + chunk * 8;
        float4 a = *(const float4*)s;
        float4 b = *(const float4*)(s + 4);
        v[0] = a.x; v[1] = a.y; v[2] = a.z; v[3] = a.w;
        v[4] = b.x; v[5] = b.y; v[6] = b.z; v[7] = b.w;
    } else if (chunk == 37) {                           // emb tail 296..299 + pad
        float4 a = *(const float4*)(er + 296);
        v[0] = a.x; v[1] = a.y; v[2] = a.z; v[3] = a.w;
        v[4] = 0.f; v[5] = 0.f; v[6] = 0.f; v[7] = 0.f;
    } else if (chunk <= 41) {                           // pos (stride 120 B: scalar, guarded)
        int k0 = chunk * 8 - 304;
        #pragma unroll
        for (int i = 0; i < 8; ++i) v[i] = (k0 + i < 30) ? pr[k0 + i] : 0.f;
    } else if (chunk <= 45) {                           // ner
        int k0 = chunk * 8 - 336;
        #pragma unroll
        for (int i = 0; i < 8; ++i) v[i] = (k0 + i < 30) ? nr[k0 + i] : 0.f;
    } else {
        #pragma unroll
        for (int i = 0; i < 8; ++i) v[i] = 0.f;
    }
    short8 r;
    #pragma unroll
    for (int i = 0; i < 8; ++i) r[i] = (short)f2b(v[i]);
    return r;
}

// ---------------- weight prep + colnz zero
__global__ void prep_weights(const float* __restrict__ W0, const float* __restrict__ W1,
                             short* __restrict__ W0p, short* __restrict__ W1p,
                             unsigned* __restrict__ colnz) {
    int idx = blockIdx.x * 256 + threadIdx.x;
    if (idx < NROWS) colnz[idx] = 0u;
    if (idx < NP * KP1) {
        int n = idx / KP1, kp = idx - n * KP1;
        float v = 0.f;
        if (n < MEM) {
            if (kp < 300)                   v = W0[n * IN_DIM + kp];
            else if (kp >= 304 && kp < 334) v = W0[n * IN_DIM + 300 + (kp - 304)];
            else if (kp >= 336 && kp < 366) v = W0[n * IN_DIM + 330 + (kp - 336)];
        }
        W0p[idx] = (short)f2b(v);
    } else {
        int i2 = idx - NP * KP1;
        if (i2 < NP * NP) {
            int n = i2 >> 8, k = i2 & 255;
            float v = (n < MEM && k < MEM) ? W1[n * MEM + k] : 0.f;
            W1p[i2] = (short)f2b(v);
        }
    }
}

// ---------------- adj row pass: rowsum/dinv, S = (A+I) bf16 [B][256][256], colnz flags
__global__ void adjrow_kernel(const float* __restrict__ adj, float* __restrict__ dinv,
                              float* __restrict__ rsum, unsigned short* __restrict__ Sbf,
                              unsigned* __restrict__ colnz) {
    int row = blockIdx.x * 4 + (threadIdx.x >> 6);
    int lane = threadIdx.x & 63;
    const float4* ar = (const float4*)(adj + (size_t)row * NL);
    float4 v = ar[lane];
    float s = v.x + v.y + v.z + v.w;
    #pragma unroll
    for (int off = 32; off >= 1; off >>= 1) s += __shfl_xor(s, off);
    int rloc = row & 255;
    float d0 = v.x + ((lane * 4 + 0) == rloc ? 1.f : 0.f);
    float d1 = v.y + ((lane * 4 + 1) == rloc ? 1.f : 0.f);
    float d2 = v.z + ((lane * 4 + 2) == rloc ? 1.f : 0.f);
    float d3 = v.w + ((lane * 4 + 3) == rloc ? 1.f : 0.f);
    ushort4 st; st.x = f2b(d0); st.y = f2b(d1); st.z = f2b(d2); st.w = f2b(d3);
    *(ushort4*)(Sbf + (size_t)row * NL + lane * 4) = st;
    if (lane == 0) { rsum[row] = s; dinv[row] = 1.0f / (s + 1.0f); }
    unsigned* cz = colnz + ((row >> 8) << 8);
    if (v.x != 0.f) atomicOr(&cz[lane * 4 + 0], 1u);
    if (v.y != 0.f) atomicOr(&cz[lane * 4 + 1], 1u);
    if (v.z != 0.f) atomicOr(&cz[lane * 4 + 2], 1u);
    if (v.w != 0.f) atomicOr(&cz[lane * 4 + 3], 1u);
}

// ---------------- FUSED per-layer, all-MFMA, double-buffered LDS + 4-DEEP register ring.
// r13 structure (A/B/S all via LDS) with the A/B global->register pipeline deepened to 4
// tiles (load for kt+4 issued at step kt -> ~3 K-steps (~900 cyc) of latency cover for
// the scattered embW gather / X1b stream).
// FINAL=0: A staging IS the embedding gather; also writes mask (folded mask_kernel).
// N-slice 64 (grid 512 = 2 blocks/CU); 8 waves 4x2, wave tile 64x32, acc[4][2].
template <int FINAL>
__global__ __launch_bounds__(512, 4) void fused_kernel(
    const short* __restrict__ A, int lda, int nkt,
    const short* __restrict__ Bp, int ldb,
    const unsigned short* __restrict__ Sbf,
    const float* __restrict__ dinv, const float* __restrict__ bias,
    const int* __restrict__ words, const int* __restrict__ pos, const int* __restrict__ ner,
    const float* __restrict__ embW, const float* __restrict__ posW,
    const float* __restrict__ nerW,
    const float* __restrict__ rsum, const unsigned* __restrict__ colnz,
    float* __restrict__ maskout,
    short* __restrict__ x1b, float* __restrict__ outx) {
    extern __shared__ char smem[];
    unsigned short* Yt = (unsigned short*)(smem + YTOFF);   // [64][YTP] bf16

    int bi = blockIdx.x;
    int batch = bi & 127, sl = bi >> 7;                 // 4 slices of a batch -> same XCD

    int tid = threadIdx.x;
    int lane = tid & 63, wid = tid >> 6;
    int wr = wid >> 1, wc = wid & 1;                    // 4 x 2 wave grid
    int lr = lane & 15, lc = lane >> 4;

    // folded mask_kernel (FINAL=0, slice-0 blocks; adjrow outputs ready at launch)
    if (FINAL == 0 && sl == 0 && tid < 256) {
        int r = batch * NL + tid;
        maskout[r] = (rsum[r] == 0.f && colnz[r] == 0u) ? 1.0f : 0.0f;
    }

    const short* Bb = Bp + (size_t)sl * 64 * ldb;
    const short* Sb = (const short*)(Sbf + (size_t)batch * NL * NL);

    // staging slots (byte offsets within a buffer)
    int r0s = tid >> 2, c0s = tid & 3;
    int r1s = r0s + 128;
    int offA0 = r0s * 64 + (c0s ^ ((r0s >> 1) & 3)) * 16;
    int offA1 = r1s * 64 + (c0s ^ ((r1s >> 1) & 3)) * 16;
    const short* Sp0 = Sb + (size_t)r0s * NL + c0s * 8;
    const short* Sp1 = Sb + (size_t)r1s * NL + c0s * 8;
    int offB = 0; const short* Bpp = nullptr;
    if (tid < 256) {
        int br = tid >> 2, bc = tid & 3;
        offB = 16384 + br * 64 + (bc ^ ((br >> 1) & 3)) * 16;
        Bpp = Bb + (size_t)br * ldb + bc * 8;
    }

    // A source: FINAL=0 -> per-row table pointers; FINAL=1 -> X1b pointers
    const short* Ap0 = nullptr; const short* Ap1 = nullptr;
    const float *er0 = nullptr, *pr0 = nullptr, *nr0 = nullptr;
    const float *er1 = nullptr, *pr1 = nullptr, *nr1 = nullptr;
    if (FINAL == 0) {
        int g0 = batch * NL + r0s, g1 = g0 + 128;
        er0 = embW + (size_t)words[g0] * 300;
        pr0 = posW + (size_t)pos[g0] * 30;
        nr0 = nerW + (size_t)ner[g0] * 30;
        er1 = embW + (size_t)words[g1] * 300;
        pr1 = posW + (size_t)pos[g1] * 30;
        nr1 = nerW + (size_t)ner[g1] * 30;
    } else {
        const short* Ab = A + (size_t)batch * NL * lda;
        Ap0 = Ab + (size_t)r0s * lda + c0s * 8;
        Ap1 = Ab + (size_t)r1s * lda + c0s * 8;
    }
    #define LOADA(kt, o0, o1) do {                                  \
        if (FINAL == 0) {                                           \
            int ch_ = (kt) * 4 + c0s;                               \
            (o0) = gather_chunk(ch_, er0, pr0, nr0);                \
            (o1) = gather_chunk(ch_, er1, pr1, nr1);                \
        } else {                                                    \
            (o0) = *(const short8*)(Ap0 + (kt) * 32);               \
            (o1) = *(const short8*)(Ap1 + (kt) * 32);               \
        }                                                           \
    } while (0)

    f32x4 acc[4][2] = {};
    short8 sA0, sA1, sB0, sB1;                          // S t0/t1 regs

    // 4-deep ring: set s holds A tile t with t%4==s (pairs aX_0/aX_1, B reg bbX)
    short8 a0_0, a0_1, a1_0, a1_1, a2_0, a2_1, a3_0, a3_1;
    short8 bb0, bb1, bb2, bb3;
    // prologue: tile 0 -> buf0 immediately; tiles 1..3 into ring
    LOADA(0, a0_0, a0_1);
    if (tid < 256) bb0 = *(const short8*)Bpp;
    *(short8*)(smem + offA0) = a0_0;
    *(short8*)(smem + offA1) = a0_1;
    if (tid < 256) *(short8*)(smem + offB) = bb0;
    LOADA(1, a1_0, a1_1);
    LOADA(2, a2_0, a2_1);
    LOADA(3, a3_0, a3_1);
    if (tid < 256) {
        bb1 = *(const short8*)(Bpp + 32);
        bb2 = *(const short8*)(Bpp + 64);
        bb3 = *(const short8*)(Bpp + 96);
    }
    __syncthreads();

    // STEP(kt, P=kt&1, WA*/WB = tile kt+1 regs, LA*/LB = ring set receiving tile kt+4)
    #define STEP(kt, P, WA0, WA1, WB, LA0, LA1, LB) do {                        \
        char* base_ = smem + (P) * BUFSZ;                                       \
        short8 af[4], bf[2];                                                    \
        _Pragma("unroll")                                                       \
        for (int mi = 0; mi < 4; ++mi) {                                        \
            int row = wr * 64 + mi * 16 + lr;                                   \
            int cs = lc ^ ((row >> 1) & 3);                                     \
            af[mi] = *(const short8*)(base_ + row * 64 + cs * 16);              \
        }                                                                       \
        _Pragma("unroll")                                                       \
        for (int ni = 0; ni < 2; ++ni) {                                        \
            int row = wc * 32 + ni * 16 + lr;                                   \
            int cs = lc ^ ((row >> 1) & 3);                                     \
            bf[ni] = *(const short8*)(base_ + 16384 + row * 64 + cs * 16);      \
        }                                                                       \
        if ((kt) + 1 < nkt) {                                                   \
            char* nb_ = smem + (1 - (P)) * BUFSZ;                               \
            *(short8*)(nb_ + offA0) = WA0;                                      \
            *(short8*)(nb_ + offA1) = WA1;                                      \
            if (tid < 256) *(short8*)(nb_ + offB) = WB;                         \
        }                                                                       \
        if ((kt) + 4 < nkt) {                                                   \
            LOADA((kt) + 4, LA0, LA1);                                          \
            if (tid < 256) LB = *(const short8*)(Bpp + ((kt) + 4) * 32);        \
        } else if ((kt) + 4 == nkt) {                                           \
            sA0 = *(const short8*)Sp0;                                          \
            sA1 = *(const short8*)Sp1;                                          \
        } else if ((kt) + 4 == nkt + 1) {                                       \
            sB0 = *(const short8*)(Sp0 + 32);                                   \
            sB1 = *(const short8*)(Sp1 + 32);                                   \
        }                                                                       \
        _Pragma("unroll")                                                       \
        for (int mi = 0; mi < 4; ++mi) {                                        \
            acc[mi][0] = __builtin_amdgcn_mfma_f32_16x16x32_bf16(af[mi], bf[0], acc[mi][0], 0, 0, 0); \
            acc[mi][1] = __builtin_amdgcn_mfma_f32_16x16x32_bf16(af[mi], bf[1], acc[mi][1], 0, 0, 0); \
        }                                                                       \
        __syncthreads();                                                        \
    } while (0)

    for (int kb = 0; kb < nkt; kb += 4) {               // nkt is 12 or 8: divisible by 4
        STEP(kb + 0, 0, a1_0, a1_1, bb1, a0_0, a0_1, bb0);
        STEP(kb + 1, 1, a2_0, a2_1, bb2, a1_0, a1_1, bb1);
        STEP(kb + 2, 0, a3_0, a3_1, bb3, a2_0, a2_1, bb2);
        STEP(kb + 3, 1, a0_0, a0_1, bb0, a3_0, a3_1, bb3);
    }
    #undef STEP
    #undef LOADA

    // Phase 2a: acc -> Yt transposed (col = y-col, 4 consecutive batch rows per 8B write)
    #pragma unroll
    for (int mi = 0; mi < 4; ++mi)
        #pragma unroll
        for (int ni = 0; ni < 2; ++ni) {
            f32x4 v = acc[mi][ni];
            ushort4 st; st.x = f2b(v[0]); st.y = f2b(v[1]); st.z = f2b(v[2]); st.w = f2b(v[3]);
            int col = wc * 32 + ni * 16 + lr;
            int row0 = wr * 64 + mi * 16 + lc * 4;
            *(ushort4*)(Yt + (size_t)col * YTP + row0) = st;
        }
    // stage S t0 -> buf0.At (buf0 free: last A read was tile nkt-2); prefetch t2
    *(short8*)(smem + offA0) = sA0;
    *(short8*)(smem + offA1) = sA1;
    sA0 = *(const short8*)(Sp0 + 64);
    sA1 = *(const short8*)(Sp1 + 64);
    __syncthreads();                                    // Yt + S t0 visible

    // Phase 2b: Zt = Yt x S, 8 K-tiles, ping-pong staging, 1 barrier/tile
    f32x4 acc2[4][2] = {};
    #pragma unroll
    for (int kt = 0; kt < 8; ++kt) {
        char* base_ = smem + (kt & 1) * BUFSZ;
        short8 ay[4], bs[2];
        #pragma unroll
        for (int mi = 0; mi < 4; ++mi)                  // a = Y^T rows (y-cols), k-contig
            ay[mi] = *(const short8*)(Yt + (size_t)(mi * 16 + lr) * YTP + kt * 32 + lc * 8);
        #pragma unroll
        for (int ni = 0; ni < 2; ++ni) {                // b = S rows (out-rows), swizzled
            int row = wid * 32 + ni * 16 + lr;
            int cs = lc ^ ((row >> 1) & 3);
            bs[ni] = *(const short8*)(base_ + row * 64 + cs * 16);
        }
        if (kt + 1 < 8) {                               // write tile kt+1; reload that set
            char* nb_ = smem + ((kt + 1) & 1) * BUFSZ;
            if ((kt & 1) == 0) {
                *(short8*)(nb_ + offA0) = sB0;
                *(short8*)(nb_ + offA1) = sB1;
                if (kt + 3 < 8) {
                    sB0 = *(const short8*)(Sp0 + (kt + 3) * 32);
                    sB1 = *(const short8*)(Sp1 + (kt + 3) * 32);
                }
            } else {
                *(short8*)(nb_ + offA0) = sA0;
                *(short8*)(nb_ + offA1) = sA1;
                if (kt + 3 < 8) {
                    sA0 = *(const short8*)(Sp0 + (kt + 3) * 32);
                    sA1 = *(const short8*)(Sp1 + (kt + 3) * 32);
                }
            }
        }
        #pragma unroll
        for (int mi = 0; mi < 4; ++mi) {
            acc2[mi][0] = __builtin_amdgcn_mfma_f32_16x16x32_bf16(ay[mi], bs[0], acc2[mi][0], 0, 0, 0);
            acc2[mi][1] = __builtin_amdgcn_mfma_f32_16x16x32_bf16(ay[mi], bs[1], acc2[mi][1], 0, 0, 0);
        }
        if (kt + 1 < 8) __syncthreads();
    }

    // Epilogue: lane holds outrow lr (fixed) x 4 consecutive y-cols per frag
    #pragma unroll
    for (int ni = 0; ni < 2; ++ni) {
        int g = batch * NL + wid * 32 + ni * 16 + lr;   // global output row
        float di = dinv[g];
        #pragma unroll
        for (int mi = 0; mi < 4; ++mi) {
            int col0 = sl * 64 + mi * 16 + lc * 4;      // global col (multiple of 4)
            float4 bv;
            if (col0 < MEM) bv = *(const float4*)(bias + col0);
            else { bv.x = 0.f; bv.y = 0.f; bv.z = 0.f; bv.w = 0.f; }
            f32x4 z = acc2[mi][ni];
            float h0 = fmaxf((z[0] + 2.f * bv.x) * di, 0.f);
            float h1 = fmaxf((z[1] + 2.f * bv.y) * di, 0.f);
            float h2 = fmaxf((z[2] + 2.f * bv.z) * di, 0.f);
            float h3 = fmaxf((z[3] + 2.f * bv.w) * di, 0.f);
            if (FINAL == 0) {
                ushort4 st; st.x = f2b(h0); st.y = f2b(h1); st.z = f2b(h2); st.w = f2b(h3);
                *(ushort4*)((unsigned short*)x1b + (size_t)g * NP + col0) = st;
            } else if (col0 < MEM) {
                float4 o; o.x = h0; o.y = h1; o.z = h2; o.w = h3;
                *(float4*)(outx + (size_t)g * MEM + col0) = o;
            }
        }
    }
}

extern "C" void kernel_launch(void* const* d_in, const int* in_sizes, int n_in,
                              void* d_out, int out_size, void* d_ws, size_t ws_size,
                              hipStream_t stream) {
    const int*   words = (const int*)d_in[0];
    const int*   pos   = (const int*)d_in[1];
    const int*   ner   = (const int*)d_in[2];
    const float* adj   = (const float*)d_in[3];
    const float* embW  = (const float*)d_in[4];
    const float* posW  = (const float*)d_in[5];
    const float* nerW  = (const float*)d_in[6];
    const float* W0    = (const float*)d_in[7];
    const float* b0    = (const float*)d_in[8];
    const float* W1    = (const float*)d_in[9];
    const float* b1    = (const float*)d_in[10];
    float* out = (float*)d_out;

    char* ws = (char*)d_ws;
    size_t off = 0;
    short* W0p = (short*)(ws + off);        off += (size_t)NP * KP1 * 2;
    short* W1p = (short*)(ws + off);        off += (size_t)NP * NP * 2;
    short* X1b = (short*)(ws + off);        off += (size_t)NROWS * NP * 2;        // 16.8 MB
    float* dinv = (float*)(ws + off);       off += (size_t)NROWS * 4;
    float* rsum = (float*)(ws + off);       off += (size_t)NROWS * 4;
    unsigned* colnz = (unsigned*)(ws + off); off += (size_t)NROWS * 4;
    unsigned short* Sbf = (unsigned short*)(ws + off); off += (size_t)NROWS * NL * 2; // 16.8 MB

    prep_weights<<<(NP * KP1 + NP * NP + 255) / 256, 256, 0, stream>>>(W0, W1, W0p, W1p, colnz);
    adjrow_kernel<<<NROWS / 4, 256, 0, stream>>>(adj, dinv, rsum, Sbf, colnz);

    const int ldsB = YTOFF + 64 * YTP * 2;   // 74,752 B
    fused_kernel<0><<<NB * 4, 512, ldsB, stream>>>(nullptr, KP1, KP1 / 32, W0p, KP1,
                                                   Sbf, dinv, b0,
                                                   words, pos, ner, embW, posW, nerW,
                                                   rsum, colnz, out + OUT_X,
                                                   X1b, nullptr);
    fused_kernel<1><<<NB * 4, 512, ldsB, stream>>>(X1b, NP, NP / 32, W1p, NP,
                                                   Sbf, dinv, b1,
                                                   nullptr, nullptr, nullptr, nullptr, nullptr, nullptr,
                                                   nullptr, nullptr, nullptr,
                                                   nullptr, out);
}

// Round 16
// 81.962 us; speedup vs baseline: 1.3152x; 1.3152x over previous
//
#include <hip/hip_runtime.h>
#include <hip/hip_bf16.h>
#include <stdint.h>

typedef __attribute__((ext_vector_type(8))) short short8;
typedef __attribute__((ext_vector_type(4))) float f32x4;

#define NB 128
#define NL 256
#define NROWS 32768        // B*L
#define IN_DIM 360
#define KP1 384            // padded K for layer-1 GEMM (permuted layout)
#define MEM 200
#define NP 256             // padded N
#define OUT_X (NROWS * MEM)
#define YTP 264            // Yt pitch in bf16 (528 B rows)
#define BUFSZ 20480        // one staging buffer: At 16K + Bt 4K
#define YTOFF 40960        // Yt offset in smem

// Permuted K layout for x/W0p (keeps every 8-col chunk single-table):
//   kp 0..299 emb | kp 304..333 pos | kp 336..365 ner | else zero
// Chunk id c = kp/8: 0..36 emb-full | 37 emb-tail | 38..41 pos | 42..45 ner | 46,47 zero

__device__ __forceinline__ unsigned short f2b(float f) {
    unsigned u = __builtin_bit_cast(unsigned, f);
    unsigned r = (u + 0x7FFFu + ((u >> 16) & 1u)) >> 16;
    return (unsigned short)r;
}

// gather one 8-col chunk of the (permuted) embedding row as bf16
__device__ __forceinline__ short8 gather_chunk(int chunk, const float* __restrict__ er,
                                               const float* __restrict__ pr,
                                               const float* __restrict__ nr) {
    float v[8];
    if (chunk < 37) {                                   // emb, 16B-aligned (stride 1200 B)
        const float* s = er + chunk * 8;
        float4 a = *(const float4*)s;
        float4 b = *(const float4*)(s + 4);
        v[0] = a.x; v[1] = a.y; v[2] = a.z; v[3] = a.w;
        v[4] = b.x; v[5] = b.y; v[6] = b.z; v[7] = b.w;
    } else if (chunk == 37) {                           // emb tail 296..299 + pad
        float4 a = *(const float4*)(er + 296);
        v[0] = a.x; v[1] = a.y; v[2] = a.z; v[3] = a.w;
        v[4] = 0.f; v[5] = 0.f; v[6] = 0.f; v[7] = 0.f;
    } else if (chunk <= 41) {                           // pos (stride 120 B: scalar, guarded)
        int k0 = chunk * 8 - 304;
        #pragma unroll
        for (int i = 0; i < 8; ++i) v[i] = (k0 + i < 30) ? pr[k0 + i] : 0.f;
    } else if (chunk <= 45) {                           // ner
        int k0 = chunk * 8 - 336;
        #pragma unroll
        for (int i = 0; i < 8; ++i) v[i] = (k0 + i < 30) ? nr[k0 + i] : 0.f;
    } else {
        #pragma unroll
        for (int i = 0; i < 8; ++i) v[i] = 0.f;
    }
    short8 r;
    #pragma unroll
    for (int i = 0; i < 8; ++i) r[i] = (short)f2b(v[i]);
    return r;
}

// ---------------- weight prep + colnz zero
__global__ void prep_weights(const float* __restrict__ W0, const float* __restrict__ W1,
                             short* __restrict__ W0p, short* __restrict__ W1p,
                             unsigned* __restrict__ colnz) {
    int idx = blockIdx.x * 256 + threadIdx.x;
    if (idx < NROWS) colnz[idx] = 0u;
    if (idx < NP * KP1) {
        int n = idx / KP1, kp = idx - n * KP1;
        float v = 0.f;
        if (n < MEM) {
            if (kp < 300)                   v = W0[n * IN_DIM + kp];
            else if (kp >= 304 && kp < 334) v = W0[n * IN_DIM + 300 + (kp - 304)];
            else if (kp >= 336 && kp < 366) v = W0[n * IN_DIM + 330 + (kp - 336)];
        }
        W0p[idx] = (short)f2b(v);
    } else {
        int i2 = idx - NP * KP1;
        if (i2 < NP * NP) {
            int n = i2 >> 8, k = i2 & 255;
            float v = (n < MEM && k < MEM) ? W1[n * MEM + k] : 0.f;
            W1p[i2] = (short)f2b(v);
        }
    }
}

// ---------------- adj row pass: rowsum/dinv, S = (A+I) bf16 [B][256][256], colnz flags
__global__ void adjrow_kernel(const float* __restrict__ adj, float* __restrict__ dinv,
                              float* __restrict__ rsum, unsigned short* __restrict__ Sbf,
                              unsigned* __restrict__ colnz) {
    int row = blockIdx.x * 4 + (threadIdx.x >> 6);
    int lane = threadIdx.x & 63;
    const float4* ar = (const float4*)(adj + (size_t)row * NL);
    float4 v = ar[lane];
    float s = v.x + v.y + v.z + v.w;
    #pragma unroll
    for (int off = 32; off >= 1; off >>= 1) s += __shfl_xor(s, off);
    int rloc = row & 255;
    float d0 = v.x + ((lane * 4 + 0) == rloc ? 1.f : 0.f);
    float d1 = v.y + ((lane * 4 + 1) == rloc ? 1.f : 0.f);
    float d2 = v.z + ((lane * 4 + 2) == rloc ? 1.f : 0.f);
    float d3 = v.w + ((lane * 4 + 3) == rloc ? 1.f : 0.f);
    ushort4 st; st.x = f2b(d0); st.y = f2b(d1); st.z = f2b(d2); st.w = f2b(d3);
    *(ushort4*)(Sbf + (size_t)row * NL + lane * 4) = st;
    if (lane == 0) { rsum[row] = s; dinv[row] = 1.0f / (s + 1.0f); }
    unsigned* cz = colnz + ((row >> 8) << 8);
    if (v.x != 0.f) atomicOr(&cz[lane * 4 + 0], 1u);
    if (v.y != 0.f) atomicOr(&cz[lane * 4 + 1], 1u);
    if (v.z != 0.f) atomicOr(&cz[lane * 4 + 2], 1u);
    if (v.w != 0.f) atomicOr(&cz[lane * 4 + 3], 1u);
}

// ---------------- FUSED per-layer, all-MFMA, double-buffered (r13 structure).
// FINAL=0: A-tile staging IS the embedding gather; also writes mask (folded mask_kernel).
// FINAL=1: A-tile staged from X1b.
// N-slice 64 (grid 512 = 2 blocks/CU); 8 waves 4x2, wave tile 64x32, acc[4][2].
// Phase 1: Y = X@W^T, LDS dbuf, 1 barrier/K-tile, reg prefetch 2 tiles deep; S t0/t1 in tail.
// Phase 2a: acc -> Yt[64][YTP] bf16 transposed.
// Phase 2b: Zt = mfma(a=Yt, b=S) K=256 in 8 tiles, S ping-pong, 1 barrier/tile, unrolled.
template <int FINAL>
__global__ __launch_bounds__(512, 4) void fused_kernel(
    const short* __restrict__ A, int lda, int nkt,
    const short* __restrict__ Bp, int ldb,
    const unsigned short* __restrict__ Sbf,
    const float* __restrict__ dinv, const float* __restrict__ bias,
    const int* __restrict__ words, const int* __restrict__ pos, const int* __restrict__ ner,
    const float* __restrict__ embW, const float* __restrict__ posW,
    const float* __restrict__ nerW,
    const float* __restrict__ rsum, const unsigned* __restrict__ colnz,
    float* __restrict__ maskout,
    short* __restrict__ x1b, float* __restrict__ outx) {
    extern __shared__ char smem[];
    unsigned short* Yt = (unsigned short*)(smem + YTOFF);   // [64][YTP] bf16

    int bi = blockIdx.x;
    int batch = bi & 127, sl = bi >> 7;                 // 4 slices of a batch -> same XCD

    int tid = threadIdx.x;
    int lane = tid & 63, wid = tid >> 6;
    int wr = wid >> 1, wc = wid & 1;                    // 4 x 2 wave grid
    int lr = lane & 15, lc = lane >> 4;

    // folded mask_kernel (FINAL=0, slice-0 blocks; adjrow outputs ready at launch)
    if (FINAL == 0 && sl == 0 && tid < 256) {
        int r = batch * NL + tid;
        maskout[r] = (rsum[r] == 0.f && colnz[r] == 0u) ? 1.0f : 0.0f;
    }

    const short* Bb = Bp + (size_t)sl * 64 * ldb;
    const short* Sb = (const short*)(Sbf + (size_t)batch * NL * NL);

    // staging slots (byte offsets within a buffer)
    int r0s = tid >> 2, c0s = tid & 3;
    int r1s = r0s + 128;
    int offA0 = r0s * 64 + (c0s ^ ((r0s >> 1) & 3)) * 16;
    int offA1 = r1s * 64 + (c0s ^ ((r1s >> 1) & 3)) * 16;
    const short* Sp0 = Sb + (size_t)r0s * NL + c0s * 8;
    const short* Sp1 = Sb + (size_t)r1s * NL + c0s * 8;
    int offB = 0; const short* Bpp = nullptr;
    if (tid < 256) {
        int br = tid >> 2, bc = tid & 3;
        offB = 16384 + br * 64 + (bc ^ ((br >> 1) & 3)) * 16;
        Bpp = Bb + (size_t)br * ldb + bc * 8;
    }

    // A source: FINAL=0 -> per-row table pointers; FINAL=1 -> X1b pointers
    const short* Ap0 = nullptr; const short* Ap1 = nullptr;
    const float *er0 = nullptr, *pr0 = nullptr, *nr0 = nullptr;
    const float *er1 = nullptr, *pr1 = nullptr, *nr1 = nullptr;
    if (FINAL == 0) {
        int g0 = batch * NL + r0s, g1 = g0 + 128;
        er0 = embW + (size_t)words[g0] * 300;
        pr0 = posW + (size_t)pos[g0] * 30;
        nr0 = nerW + (size_t)ner[g0] * 30;
        er1 = embW + (size_t)words[g1] * 300;
        pr1 = posW + (size_t)pos[g1] * 30;
        nr1 = nerW + (size_t)ner[g1] * 30;
    } else {
        const short* Ab = A + (size_t)batch * NL * lda;
        Ap0 = Ab + (size_t)r0s * lda + c0s * 8;
        Ap1 = Ab + (size_t)r1s * lda + c0s * 8;
    }
    #define LOADA(kt, o0, o1) do {                                  \
        if (FINAL == 0) {                                           \
            int ch_ = (kt) * 4 + c0s;                               \
            (o0) = gather_chunk(ch_, er0, pr0, nr0);                \
            (o1) = gather_chunk(ch_, er1, pr1, nr1);                \
        } else {                                                    \
            (o0) = *(const short8*)(Ap0 + (kt) * 32);               \
            (o1) = *(const short8*)(Ap1 + (kt) * 32);               \
        }                                                           \
    } while (0)

    f32x4 acc[4][2] = {};
    // prologue: tile 0 -> buf0; load tile 1
    short8 aR0, aR1, bR;
    LOADA(0, aR0, aR1);
    if (tid < 256) bR = *(const short8*)Bpp;
    *(short8*)(smem + offA0) = aR0;
    *(short8*)(smem + offA1) = aR1;
    if (tid < 256) *(short8*)(smem + offB) = bR;
    LOADA(1, aR0, aR1);
    if (tid < 256) bR = *(const short8*)(Bpp + 32);
    __syncthreads();

    short8 sA0, sA1, sB0, sB1;                          // S t0/t1 regs
    for (int kt = 0; kt < nkt; ++kt) {
        char* base_ = smem + (kt & 1) * BUFSZ;
        short8 af[4], bf[2];
        #pragma unroll
        for (int mi = 0; mi < 4; ++mi) {
            int row = wr * 64 + mi * 16 + lr;
            int cs = lc ^ ((row >> 1) & 3);
            af[mi] = *(const short8*)(base_ + row * 64 + cs * 16);
        }
        #pragma unroll
        for (int ni = 0; ni < 2; ++ni) {
            int row = wc * 32 + ni * 16 + lr;
            int cs = lc ^ ((row >> 1) & 3);
            bf[ni] = *(const short8*)(base_ + 16384 + row * 64 + cs * 16);
        }
        if (kt + 1 < nkt) {                             // write tile kt+1 to other buffer
            char* nb_ = smem + ((kt + 1) & 1) * BUFSZ;
            *(short8*)(nb_ + offA0) = aR0;
            *(short8*)(nb_ + offA1) = aR1;
            if (tid < 256) *(short8*)(nb_ + offB) = bR;
        }
        if (kt + 2 < nkt) {                             // prefetch tile kt+2
            LOADA(kt + 2, aR0, aR1);
            if (tid < 256) bR = *(const short8*)(Bpp + (kt + 2) * 32);
        } else if (kt + 2 == nkt) {                     // tail: S t0
            sA0 = *(const short8*)Sp0;
            sA1 = *(const short8*)Sp1;
        } else if (kt + 2 == nkt + 1) {                 // tail: S t1
            sB0 = *(const short8*)(Sp0 + 32);
            sB1 = *(const short8*)(Sp1 + 32);
        }
        #pragma unroll
        for (int mi = 0; mi < 4; ++mi)
            #pragma unroll
            for (int ni = 0; ni < 2; ++ni)
                acc[mi][ni] = __builtin_amdgcn_mfma_f32_16x16x32_bf16(af[mi], bf[ni], acc[mi][ni], 0, 0, 0);
        __syncthreads();
    }
    #undef LOADA

    // Phase 2a: acc -> Yt transposed (col = y-col, 4 consecutive batch rows per 8B write)
    #pragma unroll
    for (int mi = 0; mi < 4; ++mi)
        #pragma unroll
        for (int ni = 0; ni < 2; ++ni) {
            f32x4 v = acc[mi][ni];
            ushort4 st; st.x = f2b(v[0]); st.y = f2b(v[1]); st.z = f2b(v[2]); st.w = f2b(v[3]);
            int col = wc * 32 + ni * 16 + lr;
            int row0 = wr * 64 + mi * 16 + lc * 4;
            *(ushort4*)(Yt + (size_t)col * YTP + row0) = st;
        }
    // stage S t0 -> buf0.At (buf0 free: last read at kt=nkt-2, barrier passed); prefetch t2
    *(short8*)(smem + offA0) = sA0;
    *(short8*)(smem + offA1) = sA1;
    sA0 = *(const short8*)(Sp0 + 64);
    sA1 = *(const short8*)(Sp1 + 64);
    __syncthreads();                                    // Yt + S t0 visible

    // Phase 2b: Zt = Yt x S, 8 K-tiles, ping-pong staging, 1 barrier/tile
    f32x4 acc2[4][2] = {};
    #pragma unroll
    for (int kt = 0; kt < 8; ++kt) {
        char* base_ = smem + (kt & 1) * BUFSZ;
        short8 ay[4], bs[2];
        #pragma unroll
        for (int mi = 0; mi < 4; ++mi)                  // a = Y^T rows (y-cols), k-contig
            ay[mi] = *(const short8*)(Yt + (size_t)(mi * 16 + lr) * YTP + kt * 32 + lc * 8);
        #pragma unroll
        for (int ni = 0; ni < 2; ++ni) {                // b = S rows (out-rows), swizzled
            int row = wid * 32 + ni * 16 + lr;
            int cs = lc ^ ((row >> 1) & 3);
            bs[ni] = *(const short8*)(base_ + row * 64 + cs * 16);
        }
        if (kt + 1 < 8) {                               // write tile kt+1; reload that set
            char* nb_ = smem + ((kt + 1) & 1) * BUFSZ;
            if ((kt & 1) == 0) {
                *(short8*)(nb_ + offA0) = sB0;
                *(short8*)(nb_ + offA1) = sB1;
                if (kt + 3 < 8) {
                    sB0 = *(const short8*)(Sp0 + (kt + 3) * 32);
                    sB1 = *(const short8*)(Sp1 + (kt + 3) * 32);
                }
            } else {
                *(short8*)(nb_ + offA0) = sA0;
                *(short8*)(nb_ + offA1) = sA1;
                if (kt + 3 < 8) {
                    sA0 = *(const short8*)(Sp0 + (kt + 3) * 32);
                    sA1 = *(const short8*)(Sp1 + (kt + 3) * 32);
                }
            }
        }
        #pragma unroll
        for (int mi = 0; mi < 4; ++mi)
            #pragma unroll
            for (int ni = 0; ni < 2; ++ni)
                acc2[mi][ni] = __builtin_amdgcn_mfma_f32_16x16x32_bf16(ay[mi], bs[ni], acc2[mi][ni], 0, 0, 0);
        if (kt + 1 < 8) __syncthreads();
    }

    // Epilogue: lane holds outrow lr (fixed) x 4 consecutive y-cols per frag
    #pragma unroll
    for (int ni = 0; ni < 2; ++ni) {
        int g = batch * NL + wid * 32 + ni * 16 + lr;   // global output row
        float di = dinv[g];
        #pragma unroll
        for (int mi = 0; mi < 4; ++mi) {
            int col0 = sl * 64 + mi * 16 + lc * 4;      // global col (multiple of 4)
            float4 bv;
            if (col0 < MEM) bv = *(const float4*)(bias + col0);
            else { bv.x = 0.f; bv.y = 0.f; bv.z = 0.f; bv.w = 0.f; }
            f32x4 z = acc2[mi][ni];
            float h0 = fmaxf((z[0] + 2.f * bv.x) * di, 0.f);
            float h1 = fmaxf((z[1] + 2.f * bv.y) * di, 0.f);
            float h2 = fmaxf((z[2] + 2.f * bv.z) * di, 0.f);
            float h3 = fmaxf((z[3] + 2.f * bv.w) * di, 0.f);
            if (FINAL == 0) {
                ushort4 st; st.x = f2b(h0); st.y = f2b(h1); st.z = f2b(h2); st.w = f2b(h3);
                *(ushort4*)((unsigned short*)x1b + (size_t)g * NP + col0) = st;
            } else if (col0 < MEM) {
                float4 o; o.x = h0; o.y = h1; o.z = h2; o.w = h3;
                *(float4*)(outx + (size_t)g * MEM + col0) = o;
            }
        }
    }
}

extern "C" void kernel_launch(void* const* d_in, const int* in_sizes, int n_in,
                              void* d_out, int out_size, void* d_ws, size_t ws_size,
                              hipStream_t stream) {
    const int*   words = (const int*)d_in[0];
    const int*   pos   = (const int*)d_in[1];
    const int*   ner   = (const int*)d_in[2];
    const float* adj   = (const float*)d_in[3];
    const float* embW  = (const float*)d_in[4];
    const float* posW  = (const float*)d_in[5];
    const float* nerW  = (const float*)d_in[6];
    const float* W0    = (const float*)d_in[7];
    const float* b0    = (const float*)d_in[8];
    const float* W1    = (const float*)d_in[9];
    const float* b1    = (const float*)d_in[10];
    float* out = (float*)d_out;

    char* ws = (char*)d_ws;
    size_t off = 0;
    short* W0p = (short*)(ws + off);        off += (size_t)NP * KP1 * 2;
    short* W1p = (short*)(ws + off);        off += (size_t)NP * NP * 2;
    short* X1b = (short*)(ws + off);        off += (size_t)NROWS * NP * 2;        // 16.8 MB
    float* dinv = (float*)(ws + off);       off += (size_t)NROWS * 4;
    float* rsum = (float*)(ws + off);       off += (size_t)NROWS * 4;
    unsigned* colnz = (unsigned*)(ws + off); off += (size_t)NROWS * 4;
    unsigned short* Sbf = (unsigned short*)(ws + off); off += (size_t)NROWS * NL * 2; // 16.8 MB

    prep_weights<<<(NP * KP1 + NP * NP + 255) / 256, 256, 0, stream>>>(W0, W1, W0p, W1p, colnz);
    adjrow_kernel<<<NROWS / 4, 256, 0, stream>>>(adj, dinv, rsum, Sbf, colnz);

    const int ldsB = YTOFF + 64 * YTP * 2;   // 74,752 B
    fused_kernel<0><<<NB * 4, 512, ldsB, stream>>>(nullptr, KP1, KP1 / 32, W0p, KP1,
                                                   Sbf, dinv, b0,
                                                   words, pos, ner, embW, posW, nerW,
                                                   rsum, colnz, out + OUT_X,
                                                   X1b, nullptr);
    fused_kernel<1><<<NB * 4, 512, ldsB, stream>>>(X1b, NP, NP / 32, W1p, NP,
                                                   Sbf, dinv, b1,
                                                   nullptr, nullptr, nullptr, nullptr, nullptr, nullptr,
                                                   nullptr, nullptr, nullptr,
                                                   nullptr, out);
}